// Round 7
// baseline (169.299 us; speedup 1.0000x reference)
//
#include <hip/hip_runtime.h>

#define CDIV(a,b) (((a)+(b)-1)/(b))

typedef __attribute__((ext_vector_type(8)))  short short8v;
typedef __attribute__((ext_vector_type(4)))  short short4v;
typedef __attribute__((ext_vector_type(16))) float f32x16;

__device__ inline unsigned short f2bf(float x) {
    unsigned u = __builtin_bit_cast(unsigned, x);
    u += 0x7fffu + ((u >> 16) & 1u);          // round-to-nearest-even
    return (unsigned short)(u >> 16);
}

// ---------------------------------------------------------------------------
// prep: feats->bf16 [N+1,4]; zero rows x1h[N], x2h[M]; pack W1/W2/W3 into
// lane-order bf16 layouts so every MFMA B-load is a coalesced 1KB wave read.
//   w1p[m*512 + l*8 + e]         = W1[4m + 2h + (e>>2)][e&3][r]   (slots>26 ->0)
//   w2p[k*1024 + p*512 + l*8 +e] = W2[k][p*16 + h*8 + e][r]
//   w3p[k*1024 + p*512 + l*8 +e] = (r<2) ? W3[k][p*16 + h*8 + e][r] : 0
// where l = lane, h = l>>5, r = l&31, p = half (c<16 / c>=16).
// ---------------------------------------------------------------------------
__global__ __launch_bounds__(256) void prep_k(
    const float* __restrict__ feats, const float* __restrict__ W1,
    const float* __restrict__ W2, const float* __restrict__ W3,
    unsigned short* __restrict__ featsh, unsigned short* __restrict__ x1h,
    unsigned short* __restrict__ x2h,
    unsigned short* __restrict__ w1p, unsigned short* __restrict__ w2p,
    unsigned short* __restrict__ w3p, int N, int M)
{
    int i = blockIdx.x * 256 + threadIdx.x;
    if (i < N) {
        float4 f = *reinterpret_cast<const float4*>(feats + (size_t)i * 4);
        ushort4 h; h.x = f2bf(f.x); h.y = f2bf(f.y); h.z = f2bf(f.z); h.w = f2bf(f.w);
        *reinterpret_cast<ushort4*>(featsh + (size_t)i * 4) = h;
        return;
    }
    if (i == N) {
        *reinterpret_cast<ushort4*>(featsh + (size_t)N * 4) = make_ushort4(0, 0, 0, 0);
        #pragma unroll
        for (int t = 0; t < 8; ++t) {
            *reinterpret_cast<ushort4*>(x1h + (size_t)N * 32 + t * 4) = make_ushort4(0, 0, 0, 0);
            *reinterpret_cast<ushort4*>(x2h + (size_t)M * 32 + t * 4) = make_ushort4(0, 0, 0, 0);
        }
        return;
    }
    int j = i - (N + 1);
    if (j < 4096) {                          // w1p: [8][64][8]
        int m = j >> 9, t = j & 511, l = t >> 3, e = t & 7;
        int h = l >> 5, r = l & 31;
        int kk = h * 8 + e, slot = 4 * m + (kk >> 2), c = kk & 3;
        float v = (slot < 27) ? W1[slot * 128 + c * 32 + r] : 0.f;
        w1p[j] = f2bf(v);
        return;
    }
    j -= 4096;
    if (j < 27 * 1024) {                     // w2p: [27][2][64][8]
        int k = j >> 10, idx = j & 1023, p = idx >> 9, t = idx & 511;
        int l = t >> 3, e = t & 7, h = l >> 5, r = l & 31;
        int c = p * 16 + h * 8 + e;
        w2p[j] = f2bf(W2[k * 1024 + c * 32 + r]);
        return;
    }
    j -= 27 * 1024;
    if (j < 27 * 1024) {                     // w3p: [27][2][64][8]
        int k = j >> 10, idx = j & 1023, p = idx >> 9, t = idx & 511;
        int l = t >> 3, e = t & 7, h = l >> 5, r = l & 31;
        int c = p * 16 + h * 8 + e;
        float v = (r < 2) ? W3[k * 64 + c * 2 + r] : 0.f;
        w3p[j] = f2bf(v);
    }
}

// ---------------------------------------------------------------------------
// conv1: featsh [N+1,4] x w1p -> x1h [N+1,32] bf16.
// 32x32x16 MFMA, k-folded: 8 MFMAs cover 32 slots x 4 ch for 32 rows/wave.
// ---------------------------------------------------------------------------
__global__ __launch_bounds__(256) void conv1_k(
    const unsigned short* __restrict__ featsh, const unsigned short* __restrict__ w1p,
    const int* __restrict__ g1, const int* __restrict__ s1,
    unsigned short* __restrict__ x1h, int N)
{
    int tid = threadIdx.x;
    int l = tid & 63, wv = tid >> 6;
    int r = l & 31, h = l >> 5;
    int rbase = blockIdx.x * 128 + wv * 32;
    int j = rbase + r;
    int jc = j < N ? j : N - 1;

    int gm[8][2];
    #pragma unroll
    for (int m = 0; m < 8; ++m)
        #pragma unroll
        for (int t = 0; t < 2; ++t) {
            int slot = 4 * m + 2 * h + t;
            int v = N;
            if (slot < 27 && j < N) {
                int s = s1[(size_t)slot * N + jc];
                int g = g1[(size_t)slot * N + jc];
                v = (s != N) ? g : N;
            }
            gm[m][t] = v;
        }

    f32x16 acc = {};
    const char* fb = (const char*)featsh;
    const char* wb = (const char*)w1p;
    #pragma unroll
    for (int m = 0; m < 8; ++m) {
        short4v lo = *(const short4v*)(fb + (size_t)gm[m][0] * 8);
        short4v hi = *(const short4v*)(fb + (size_t)gm[m][1] * 8);
        short8v a = __builtin_shufflevector(lo, hi, 0, 1, 2, 3, 4, 5, 6, 7);
        short8v b = *(const short8v*)(wb + m * 1024 + l * 16);   // coalesced 1KB
        acc = __builtin_amdgcn_mfma_f32_32x32x16_bf16(a, b, acc, 0, 0, 0);
    }
    #pragma unroll
    for (int reg = 0; reg < 16; ++reg) {
        int row = (reg & 3) + 8 * (reg >> 2) + 4 * h;
        int j2 = rbase + row;
        if (j2 < N) x1h[(size_t)j2 * 32 + r] = f2bf(acc[reg]);
    }
}

// ---------------------------------------------------------------------------
// conv2: x1h [N+1,32] bf16 x w2p -> x2h [M+1,32] bf16.
// 32 rows/wave, per-lane global gather A, coalesced packed B, no LDS/sync.
// ---------------------------------------------------------------------------
__global__ __launch_bounds__(256) void conv2_k(
    const unsigned short* __restrict__ x1h, const unsigned short* __restrict__ w2p,
    const int* __restrict__ g2, const int* __restrict__ s2,
    unsigned short* __restrict__ x2h, int M, int N)
{
    int tid = threadIdx.x;
    int l = tid & 63, wv = tid >> 6;
    int r = l & 31, h = l >> 5;
    int rbase = blockIdx.x * 128 + wv * 32;
    int j = rbase + r;
    int jc = j < M ? j : M - 1;

    int gm[27];
    #pragma unroll
    for (int k = 0; k < 27; ++k) {
        int s = s2[(size_t)k * M + jc];
        int g = g2[(size_t)k * M + jc];
        gm[k] = (j < M && s != M) ? g : N;      // row N of x1h is zeros
    }

    f32x16 acc = {};
    const char* xb = (const char*)x1h;
    const char* wb = (const char*)w2p;
    #pragma unroll
    for (int k = 0; k < 27; ++k) {
        const char* xr = xb + (size_t)gm[k] * 64;
        short8v a0 = *(const short8v*)(xr + h * 16);          // ch h*8..+8
        short8v a1 = *(const short8v*)(xr + 32 + h * 16);     // ch 16+h*8..+8
        short8v b0 = *(const short8v*)(wb + k * 2048 + l * 16);        // 1KB coalesced
        short8v b1 = *(const short8v*)(wb + k * 2048 + 1024 + l * 16); // 1KB coalesced
        acc = __builtin_amdgcn_mfma_f32_32x32x16_bf16(a0, b0, acc, 0, 0, 0);
        acc = __builtin_amdgcn_mfma_f32_32x32x16_bf16(a1, b1, acc, 0, 0, 0);
    }
    #pragma unroll
    for (int reg = 0; reg < 16; ++reg) {
        int row = (reg & 3) + 8 * (reg >> 2) + 4 * h;
        int j2 = rbase + row;
        if (j2 < M) x2h[(size_t)j2 * 32 + r] = f2bf(acc[reg]);
    }
}

// ---------------------------------------------------------------------------
// conv3: x2h [M+1,32] bf16 x w3p -> out [M,2] f32. Same gather-GEMM as conv2;
// only lanes r<2 carry nonzero B columns and store.
// ---------------------------------------------------------------------------
__global__ __launch_bounds__(256) void conv3_k(
    const unsigned short* __restrict__ x2h, const unsigned short* __restrict__ w3p,
    const int* __restrict__ g3, const int* __restrict__ s3,
    float* __restrict__ out, int M)
{
    int tid = threadIdx.x;
    int l = tid & 63, wv = tid >> 6;
    int r = l & 31, h = l >> 5;
    int rbase = blockIdx.x * 128 + wv * 32;
    int j = rbase + r;
    int jc = j < M ? j : M - 1;

    int gm[27];
    #pragma unroll
    for (int k = 0; k < 27; ++k) {
        int s = s3[(size_t)k * M + jc];
        int g = g3[(size_t)k * M + jc];
        gm[k] = (j < M && s != M) ? g : M;      // row M of x2h is zeros
    }

    f32x16 acc = {};
    const char* xb = (const char*)x2h;
    const char* wb = (const char*)w3p;
    #pragma unroll
    for (int k = 0; k < 27; ++k) {
        const char* xr = xb + (size_t)gm[k] * 64;
        short8v a0 = *(const short8v*)(xr + h * 16);
        short8v a1 = *(const short8v*)(xr + 32 + h * 16);
        short8v b0 = *(const short8v*)(wb + k * 2048 + l * 16);
        short8v b1 = *(const short8v*)(wb + k * 2048 + 1024 + l * 16);
        acc = __builtin_amdgcn_mfma_f32_32x32x16_bf16(a0, b0, acc, 0, 0, 0);
        acc = __builtin_amdgcn_mfma_f32_32x32x16_bf16(a1, b1, acc, 0, 0, 0);
    }
    if (r < 2) {
        #pragma unroll
        for (int reg = 0; reg < 16; ++reg) {
            int row = (reg & 3) + 8 * (reg >> 2) + 4 * h;
            int j2 = rbase + row;
            if (j2 < M) out[(size_t)j2 * 2 + r] = acc[reg];
        }
    }
}

// ---------------------------------------------------------------------------
extern "C" void kernel_launch(void* const* d_in, const int* in_sizes, int n_in,
                              void* d_out, int out_size, void* d_ws, size_t ws_size,
                              hipStream_t stream) {
    const float* feats = (const float*)d_in[0];
    const float* W1    = (const float*)d_in[1];
    const float* W2    = (const float*)d_in[2];
    const float* W3    = (const float*)d_in[3];
    const int*   g1    = (const int*)d_in[4];
    const int*   s1    = (const int*)d_in[5];
    const int*   g2    = (const int*)d_in[6];
    const int*   s2    = (const int*)d_in[7];
    const int*   g3    = (const int*)d_in[8];
    const int*   s3    = (const int*)d_in[9];

    int N = in_sizes[0] / 4;    // 200000
    int M = in_sizes[6] / 27;   // stride-2 output count

    char* wsb = (char*)d_ws;
    size_t off = 0;
    auto alloc = [&](size_t bytes) {
        char* p = wsb + off;
        off = (off + bytes + 255) & ~(size_t)255;
        return p;
    };
    unsigned short* x1h    = (unsigned short*)alloc((size_t)(N + 1) * 64); // [N+1,32] bf16
    unsigned short* x2h    = (unsigned short*)alloc((size_t)(M + 1) * 64); // [M+1,32] bf16
    unsigned short* featsh = (unsigned short*)alloc((size_t)(N + 1) * 8);  // [N+1,4]  bf16
    unsigned short* w1p    = (unsigned short*)alloc(4096 * 2);             // [8][64][8]
    unsigned short* w2p    = (unsigned short*)alloc(27 * 1024 * 2);        // [27][2][64][8]
    unsigned short* w3p    = (unsigned short*)alloc(27 * 1024 * 2);        // [27][2][64][8]
    float* out = (float*)d_out;

    int prep_items = (N + 1) + 4096 + 27 * 1024 + 27 * 1024;
    prep_k<<<CDIV(prep_items, 256), 256, 0, stream>>>(
        feats, W1, W2, W3, featsh, x1h, x2h, w1p, w2p, w3p, N, M);
    conv1_k<<<CDIV(N, 128), 256, 0, stream>>>(featsh, w1p, g1, s1, x1h, N);
    conv2_k<<<CDIV(M, 128), 256, 0, stream>>>(x1h, w2p, g2, s2, x2h, M, N);
    conv3_k<<<CDIV(M, 128), 256, 0, stream>>>(x2h, w3p, g3, s3, out, M);
}

// Round 8
// 167.212 us; speedup vs baseline: 1.0125x; 1.0125x over previous
//
#include <hip/hip_runtime.h>
#include <hip/hip_cooperative_groups.h>

namespace cg = cooperative_groups;

#define CDIV(a,b) (((a)+(b)-1)/(b))

typedef __attribute__((ext_vector_type(8)))  short short8v;
typedef __attribute__((ext_vector_type(4)))  short short4v;
typedef __attribute__((ext_vector_type(16))) float f32x16;

__device__ inline unsigned short f2bf(float x) {
    unsigned u = __builtin_bit_cast(unsigned, x);
    u += 0x7fffu + ((u >> 16) & 1u);          // round-to-nearest-even
    return (unsigned short)(u >> 16);
}

// ===========================================================================
// Stage bodies (shared by fused cooperative kernel and 4-kernel fallback)
// ===========================================================================

// ---- prep item i: feats->bf16; zero rows; pack W1/W2/W3 lane-order bf16 ----
__device__ inline void prep_item(int i,
    const float* __restrict__ feats, const float* __restrict__ W1,
    const float* __restrict__ W2, const float* __restrict__ W3,
    unsigned short* __restrict__ featsh, unsigned short* __restrict__ x1h,
    unsigned short* __restrict__ x2h,
    unsigned short* __restrict__ w1p, unsigned short* __restrict__ w2p,
    unsigned short* __restrict__ w3p, int N, int M)
{
    if (i < N) {
        float4 f = *reinterpret_cast<const float4*>(feats + (size_t)i * 4);
        ushort4 h; h.x = f2bf(f.x); h.y = f2bf(f.y); h.z = f2bf(f.z); h.w = f2bf(f.w);
        *reinterpret_cast<ushort4*>(featsh + (size_t)i * 4) = h;
        return;
    }
    if (i == N) {
        *reinterpret_cast<ushort4*>(featsh + (size_t)N * 4) = make_ushort4(0, 0, 0, 0);
        #pragma unroll
        for (int t = 0; t < 8; ++t) {
            *reinterpret_cast<ushort4*>(x1h + (size_t)N * 32 + t * 4) = make_ushort4(0, 0, 0, 0);
            *reinterpret_cast<ushort4*>(x2h + (size_t)M * 32 + t * 4) = make_ushort4(0, 0, 0, 0);
        }
        return;
    }
    int j = i - (N + 1);
    if (j < 4096) {                          // w1p: [8][64][8]
        int m = j >> 9, t = j & 511, l = t >> 3, e = t & 7;
        int h = l >> 5, r = l & 31;
        int kk = h * 8 + e, slot = 4 * m + (kk >> 2), c = kk & 3;
        float v = (slot < 27) ? W1[slot * 128 + c * 32 + r] : 0.f;
        w1p[j] = f2bf(v);
        return;
    }
    j -= 4096;
    if (j < 27 * 1024) {                     // w2p: [27][2][64][8]
        int k = j >> 10, idx = j & 1023, p = idx >> 9, t = idx & 511;
        int l = t >> 3, e = t & 7, h = l >> 5, r = l & 31;
        int c = p * 16 + h * 8 + e;
        w2p[j] = f2bf(W2[k * 1024 + c * 32 + r]);
        return;
    }
    j -= 27 * 1024;
    if (j < 27 * 1024) {                     // w3p: [27][2][64][8]
        int k = j >> 10, idx = j & 1023, p = idx >> 9, t = idx & 511;
        int l = t >> 3, e = t & 7, h = l >> 5, r = l & 31;
        int c = p * 16 + h * 8 + e;
        float v = (r < 2) ? W3[k * 64 + c * 2 + r] : 0.f;
        w3p[j] = f2bf(v);
    }
}

// ---- conv1 unit: 32 rows at rbase ----
__device__ inline void conv1_unit(int rbase, int l,
    const unsigned short* __restrict__ featsh, const unsigned short* __restrict__ w1p,
    const int* __restrict__ g1, const int* __restrict__ s1,
    unsigned short* __restrict__ x1h, int N)
{
    int r = l & 31, h = l >> 5;
    int j = rbase + r;
    int jc = j < N ? j : N - 1;

    int gm[8][2];
    #pragma unroll
    for (int m = 0; m < 8; ++m)
        #pragma unroll
        for (int t = 0; t < 2; ++t) {
            int slot = 4 * m + 2 * h + t;
            int v = N;
            if (slot < 27 && j < N) {
                int s = s1[(size_t)slot * N + jc];
                int g = g1[(size_t)slot * N + jc];
                v = (s != N) ? g : N;
            }
            gm[m][t] = v;
        }

    f32x16 acc = {};
    const char* fb = (const char*)featsh;
    const char* wb = (const char*)w1p;
    #pragma unroll
    for (int m = 0; m < 8; ++m) {
        short4v lo = *(const short4v*)(fb + (size_t)gm[m][0] * 8);
        short4v hi = *(const short4v*)(fb + (size_t)gm[m][1] * 8);
        short8v a = __builtin_shufflevector(lo, hi, 0, 1, 2, 3, 4, 5, 6, 7);
        short8v b = *(const short8v*)(wb + m * 1024 + l * 16);   // coalesced 1KB
        acc = __builtin_amdgcn_mfma_f32_32x32x16_bf16(a, b, acc, 0, 0, 0);
    }
    #pragma unroll
    for (int reg = 0; reg < 16; ++reg) {
        int row = (reg & 3) + 8 * (reg >> 2) + 4 * h;
        int j2 = rbase + row;
        if (j2 < N) x1h[(size_t)j2 * 32 + r] = f2bf(acc[reg]);
    }
}

// ---- conv2 unit: 32 rows at rbase ----
__device__ inline void conv2_unit(int rbase, int l,
    const unsigned short* __restrict__ x1h, const unsigned short* __restrict__ w2p,
    const int* __restrict__ g2, const int* __restrict__ s2,
    unsigned short* __restrict__ x2h, int M, int N)
{
    int r = l & 31, h = l >> 5;
    int j = rbase + r;
    int jc = j < M ? j : M - 1;

    int gm[27];
    #pragma unroll
    for (int k = 0; k < 27; ++k) {
        int s = s2[(size_t)k * M + jc];
        int g = g2[(size_t)k * M + jc];
        gm[k] = (j < M && s != M) ? g : N;      // row N of x1h is zeros
    }

    f32x16 acc = {};
    const char* xb = (const char*)x1h;
    const char* wb = (const char*)w2p;
    #pragma unroll
    for (int k = 0; k < 27; ++k) {
        const char* xr = xb + (size_t)gm[k] * 64;
        short8v a0 = *(const short8v*)(xr + h * 16);
        short8v a1 = *(const short8v*)(xr + 32 + h * 16);
        short8v b0 = *(const short8v*)(wb + k * 2048 + l * 16);
        short8v b1 = *(const short8v*)(wb + k * 2048 + 1024 + l * 16);
        acc = __builtin_amdgcn_mfma_f32_32x32x16_bf16(a0, b0, acc, 0, 0, 0);
        acc = __builtin_amdgcn_mfma_f32_32x32x16_bf16(a1, b1, acc, 0, 0, 0);
    }
    #pragma unroll
    for (int reg = 0; reg < 16; ++reg) {
        int row = (reg & 3) + 8 * (reg >> 2) + 4 * h;
        int j2 = rbase + row;
        if (j2 < M) x2h[(size_t)j2 * 32 + r] = f2bf(acc[reg]);
    }
}

// ---- conv3 unit: 32 rows at rbase ----
__device__ inline void conv3_unit(int rbase, int l,
    const unsigned short* __restrict__ x2h, const unsigned short* __restrict__ w3p,
    const int* __restrict__ g3, const int* __restrict__ s3,
    float* __restrict__ out, int M)
{
    int r = l & 31, h = l >> 5;
    int j = rbase + r;
    int jc = j < M ? j : M - 1;

    int gm[27];
    #pragma unroll
    for (int k = 0; k < 27; ++k) {
        int s = s3[(size_t)k * M + jc];
        int g = g3[(size_t)k * M + jc];
        gm[k] = (j < M && s != M) ? g : M;      // row M of x2h is zeros
    }

    f32x16 acc = {};
    const char* xb = (const char*)x2h;
    const char* wb = (const char*)w3p;
    #pragma unroll
    for (int k = 0; k < 27; ++k) {
        const char* xr = xb + (size_t)gm[k] * 64;
        short8v a0 = *(const short8v*)(xr + h * 16);
        short8v a1 = *(const short8v*)(xr + 32 + h * 16);
        short8v b0 = *(const short8v*)(wb + k * 2048 + l * 16);
        short8v b1 = *(const short8v*)(wb + k * 2048 + 1024 + l * 16);
        acc = __builtin_amdgcn_mfma_f32_32x32x16_bf16(a0, b0, acc, 0, 0, 0);
        acc = __builtin_amdgcn_mfma_f32_32x32x16_bf16(a1, b1, acc, 0, 0, 0);
    }
    if (r < 2) {
        #pragma unroll
        for (int reg = 0; reg < 16; ++reg) {
            int row = (reg & 3) + 8 * (reg >> 2) + 4 * h;
            int j2 = rbase + row;
            if (j2 < M) out[(size_t)j2 * 2 + r] = acc[reg];
        }
    }
}

// ===========================================================================
// Fused cooperative kernel: prep -> conv1 -> conv2 -> conv3 with grid.sync,
// per-stage wave-level atomic work stealing.
// ===========================================================================
__global__ __launch_bounds__(256, 2) void fused_k(
    const float* __restrict__ feats, const float* __restrict__ W1,
    const float* __restrict__ W2, const float* __restrict__ W3,
    const int* __restrict__ g1, const int* __restrict__ s1,
    const int* __restrict__ g2, const int* __restrict__ s2,
    const int* __restrict__ g3, const int* __restrict__ s3,
    unsigned short* __restrict__ featsh, unsigned short* __restrict__ x1h,
    unsigned short* __restrict__ x2h,
    unsigned short* __restrict__ w1p, unsigned short* __restrict__ w2p,
    unsigned short* __restrict__ w3p,
    float* __restrict__ out, int* __restrict__ ctr, int N, int M)
{
    cg::grid_group grid = cg::this_grid();
    int tid  = threadIdx.x;
    int gtid = blockIdx.x * 256 + tid;
    int lane = tid & 63;

    // ---- stage 0: prep (static stride) + init steal counters ----
    if (gtid == 0) { atomicExch(&ctr[0], 0); atomicExch(&ctr[1], 0); atomicExch(&ctr[2], 0); }
    int prep_items = (N + 1) + 4096 + 27 * 1024 + 27 * 1024;
    int gstride = gridDim.x * 256;
    for (int i = gtid; i < prep_items; i += gstride)
        prep_item(i, feats, W1, W2, W3, featsh, x1h, x2h, w1p, w2p, w3p, N, M);
    grid.sync();

    // ---- stage 1: conv1 (wave work-stealing, unit = 32 rows) ----
    {
        int U = CDIV(N, 32);
        int u;
        if (lane == 0) u = atomicAdd(&ctr[0], 1);
        u = __shfl(u, 0, 64);
        while (u < U) {
            conv1_unit(u * 32, lane, featsh, w1p, g1, s1, x1h, N);
            if (lane == 0) u = atomicAdd(&ctr[0], 1);
            u = __shfl(u, 0, 64);
        }
    }
    grid.sync();

    // ---- stage 2: conv2 ----
    {
        int U = CDIV(M, 32);
        int u;
        if (lane == 0) u = atomicAdd(&ctr[1], 1);
        u = __shfl(u, 0, 64);
        while (u < U) {
            conv2_unit(u * 32, lane, x1h, w2p, g2, s2, x2h, M, N);
            if (lane == 0) u = atomicAdd(&ctr[1], 1);
            u = __shfl(u, 0, 64);
        }
    }
    grid.sync();

    // ---- stage 3: conv3 ----
    {
        int U = CDIV(M, 32);
        int u;
        if (lane == 0) u = atomicAdd(&ctr[2], 1);
        u = __shfl(u, 0, 64);
        while (u < U) {
            conv3_unit(u * 32, lane, x2h, w3p, g3, s3, out, M);
            if (lane == 0) u = atomicAdd(&ctr[2], 1);
            u = __shfl(u, 0, 64);
        }
    }
}

// ===========================================================================
// Fallback standalone kernels (R7 structure, proven correct)
// ===========================================================================
__global__ __launch_bounds__(256) void prep_k(
    const float* __restrict__ feats, const float* __restrict__ W1,
    const float* __restrict__ W2, const float* __restrict__ W3,
    unsigned short* __restrict__ featsh, unsigned short* __restrict__ x1h,
    unsigned short* __restrict__ x2h,
    unsigned short* __restrict__ w1p, unsigned short* __restrict__ w2p,
    unsigned short* __restrict__ w3p, int N, int M)
{
    int i = blockIdx.x * 256 + threadIdx.x;
    int items = (N + 1) + 4096 + 27 * 1024 + 27 * 1024;
    if (i < items)
        prep_item(i, feats, W1, W2, W3, featsh, x1h, x2h, w1p, w2p, w3p, N, M);
}

__global__ __launch_bounds__(256) void conv1_k(
    const unsigned short* __restrict__ featsh, const unsigned short* __restrict__ w1p,
    const int* __restrict__ g1, const int* __restrict__ s1,
    unsigned short* __restrict__ x1h, int N)
{
    int tid = threadIdx.x;
    conv1_unit(blockIdx.x * 128 + (tid >> 6) * 32, tid & 63, featsh, w1p, g1, s1, x1h, N);
}

__global__ __launch_bounds__(256) void conv2_k(
    const unsigned short* __restrict__ x1h, const unsigned short* __restrict__ w2p,
    const int* __restrict__ g2, const int* __restrict__ s2,
    unsigned short* __restrict__ x2h, int M, int N)
{
    int tid = threadIdx.x;
    conv2_unit(blockIdx.x * 128 + (tid >> 6) * 32, tid & 63, x1h, w2p, g2, s2, x2h, M, N);
}

__global__ __launch_bounds__(256) void conv3_k(
    const unsigned short* __restrict__ x2h, const unsigned short* __restrict__ w3p,
    const int* __restrict__ g3, const int* __restrict__ s3,
    float* __restrict__ out, int M)
{
    int tid = threadIdx.x;
    conv3_unit(blockIdx.x * 128 + (tid >> 6) * 32, tid & 63, x2h, w3p, g3, s3, out, M);
}

// ===========================================================================
extern "C" void kernel_launch(void* const* d_in, const int* in_sizes, int n_in,
                              void* d_out, int out_size, void* d_ws, size_t ws_size,
                              hipStream_t stream) {
    const float* feats = (const float*)d_in[0];
    const float* W1    = (const float*)d_in[1];
    const float* W2    = (const float*)d_in[2];
    const float* W3    = (const float*)d_in[3];
    const int*   g1    = (const int*)d_in[4];
    const int*   s1    = (const int*)d_in[5];
    const int*   g2    = (const int*)d_in[6];
    const int*   s2    = (const int*)d_in[7];
    const int*   g3    = (const int*)d_in[8];
    const int*   s3    = (const int*)d_in[9];

    int N = in_sizes[0] / 4;    // 200000
    int M = in_sizes[6] / 27;   // stride-2 output count

    char* wsb = (char*)d_ws;
    size_t off = 0;
    auto alloc = [&](size_t bytes) {
        char* p = wsb + off;
        off = (off + bytes + 255) & ~(size_t)255;
        return p;
    };
    unsigned short* x1h    = (unsigned short*)alloc((size_t)(N + 1) * 64); // [N+1,32] bf16
    unsigned short* x2h    = (unsigned short*)alloc((size_t)(M + 1) * 64); // [M+1,32] bf16
    unsigned short* featsh = (unsigned short*)alloc((size_t)(N + 1) * 8);  // [N+1,4]  bf16
    unsigned short* w1p    = (unsigned short*)alloc(4096 * 2);             // [8][64][8]
    unsigned short* w2p    = (unsigned short*)alloc(27 * 1024 * 2);        // [27][2][64][8]
    unsigned short* w3p    = (unsigned short*)alloc(27 * 1024 * 2);        // [27][2][64][8]
    int*            ctr    = (int*)alloc(64);                              // steal counters
    float* out = (float*)d_out;

    // cooperative path: query co-resident capacity, clamp grid
    int nb = 0;
    hipError_t qe = hipOccupancyMaxActiveBlocksPerMultiprocessor(&nb, fused_k, 256, 0);
    bool done = false;
    if (qe == hipSuccess && nb > 0) {
        int grid = 256 * nb;
        if (grid > 2048) grid = 2048;
        void* args[] = {
            (void*)&feats, (void*)&W1, (void*)&W2, (void*)&W3,
            (void*)&g1, (void*)&s1, (void*)&g2, (void*)&s2, (void*)&g3, (void*)&s3,
            (void*)&featsh, (void*)&x1h, (void*)&x2h,
            (void*)&w1p, (void*)&w2p, (void*)&w3p,
            (void*)&out, (void*)&ctr, (void*)&N, (void*)&M };
        hipError_t e = hipLaunchCooperativeKernel(fused_k, dim3(grid), dim3(256),
                                                  args, 0, stream);
        done = (e == hipSuccess);
    }

    if (!done) {    // fallback: proven 4-kernel path
        int prep_items = (N + 1) + 4096 + 27 * 1024 + 27 * 1024;
        prep_k<<<CDIV(prep_items, 256), 256, 0, stream>>>(
            feats, W1, W2, W3, featsh, x1h, x2h, w1p, w2p, w3p, N, M);
        conv1_k<<<CDIV(N, 128), 256, 0, stream>>>(featsh, w1p, g1, s1, x1h, N);
        conv2_k<<<CDIV(M, 128), 256, 0, stream>>>(x1h, w2p, g2, s2, x2h, M, N);
        conv3_k<<<CDIV(M, 128), 256, 0, stream>>>(x2h, w3p, g3, s3, out, M);
    }
}